// Round 12
// baseline (176.339 us; speedup 1.0000x reference)
//
#include <hip/hip_runtime.h>
#include <math.h>

#define LOOKBACK 336
#define NFEAT    164
#define HORIZON  96
#define DMODEL   64
#define DSTATE   16
#define DINNER   128
#define MLPH     64
#define BATCH    512
#define XCP      132
#define NGL      2      // local groups (time segments) per block
#define GSEG     84     // timesteps per segment
#define CHK      12     // timesteps per chunk
#define NCH      7      // chunks per segment
#define HSTR     20     // hpart record stride
#define WSB      4480   // ws floats per batch: 2x(P[128][16]+D[128]) + xcl[128]

typedef float v2f __attribute__((ext_vector_type(2)));

__device__ __forceinline__ float fast_rcp(float x) { return __builtin_amdgcn_rcpf(x); }
__device__ __forceinline__ float silu_f(float x) {
    return x * fast_rcp(1.f + __expf(-x));
}

// R12 kernel 1: R8's wave-specialized chunk loop at HALF block size.
// One 256-thread block per (batch, half): 2 segments, waves 0-1 = pair-A2,
// waves 2-3 = dual-conv, all 4 waves scan. Barriers converge 4 waves (was 8);
// 4 blocks/CU (38.5KB LDS) give 4-way phase interleave (was 2).
// Each block merges its 2 segments and exports (P, sumD) via plain global
// stores; kernel boundary is the fence (no in-kernel cross-block sync -- R2).
__global__ __launch_bounds__(256, 2) void mamba_scan2(
    const float* __restrict__ x_raw,
    const float* __restrict__ embed_W, const float* __restrict__ embed_b,
    const float* __restrict__ in_W,
    const float* __restrict__ conv_W,  const float* __restrict__ conv_b,
    const float* __restrict__ xproj_W, const float* __restrict__ dt_W,
    const float* __restrict__ dt_b,    const float* __restrict__ A_log,
    float* __restrict__ ws)
{
    __shared__ __align__(16) float xrl[172];            // xrl[i]=x(half*168-3+i)
    __shared__ __align__(16) float xprojT[20*XCP];      // 10.56 KB (XCP stride: j-columns de-aliased)
    __shared__ __align__(16) float xcbuf[2][NGL][CHK*XCP]; // 25.3 KB double-buffered
    __shared__ __align__(16) float Bsh[NGL][CHK][DSTATE];
    __shared__ __align__(16) float dtraw[NGL][CHK][4];

    const int tid   = threadIdx.x;
    const int batch = blockIdx.x >> 1;
    const int half  = blockIdx.x & 1;    // segments {0,1} or {2,3}
    const int gl    = tid >> 7;          // local group 0..1 (2 waves each)
    const int ch    = tid & 127;

    // ---- staging ----
    for (int i = tid; i < 171; i += 256) {
        int t = half*168 + i - 3;
        xrl[i] = (t >= 0) ? x_raw[batch*LOOKBACK + t] : 0.f;
    }
    for (int idx = tid; idx < 20*DINNER; idx += 256) {
        int jj = idx >> 7, d = idx & 127;
        xprojT[jj*XCP + d] = xproj_W[d*36 + jj];
    }

    // ---- per-thread channel params ----
    float w1 = 0.f, w0 = 0.f;
    for (int dm = 0; dm < DMODEL; ++dm) {
        float w = in_W[dm*(2*DINNER) + ch];
        w1 = fmaf(embed_W[dm], w, w1);
        w0 = fmaf(embed_b[dm], w, w0);
    }
    const float4 cw = *(const float4*)&conv_W[ch*4];
    const float  cb = conv_b[ch];
    const float dtw0 = dt_W[ch],       dtw1 = dt_W[128 + ch],
                dtw2 = dt_W[256 + ch], dtw3 = dt_W[384 + ch];
    const float dtb_r = dt_b[ch];
    bool structured = true;
    #pragma unroll
    for (int i = 0; i < 16; ++i) {
        float a = __expf(A_log[ch*DSTATE + i]);
        float ex = (float)(i + 1);
        structured = structured && (fabsf(a - ex) < 1e-3f * ex);
    }
    const bool sfast = __all(structured);

    // pair-A2 decode (tid<120): 1 column pair x 1 tt, covers BOTH local groups
    const int a2jp = tid / 12;               // 0..9
    const int a2tt = tid - a2jp*12;          // 0..11
    // dual-conv decode (waves 2-3): channel, covers both local groups
    const int cch = tid & 127;
    __syncthreads();   // xrl/xprojT ready

    // ---- conv chunk 0 into buffer 0 (all threads, own (gl,ch)) ----
    {
        float* xw = &xcbuf[0][gl][0];
        const float* xr = &xrl[gl*GSEG];
        if (half == 0 && gl == 0) {      // zero-padded taps at sequence start
            for (int tt = 0; tt < CHK; ++tt) {
                float acc = cb;
                if (tt >= 3) acc = fmaf(fmaf(xr[tt],   w1, w0), cw.x, acc);
                if (tt >= 2) acc = fmaf(fmaf(xr[tt+1], w1, w0), cw.y, acc);
                if (tt >= 1) acc = fmaf(fmaf(xr[tt+2], w1, w0), cw.z, acc);
                acc = fmaf(fmaf(xr[tt+3], w1, w0), cw.w, acc);
                xw[tt*XCP + ch] = silu_f(acc);
            }
        } else {
            float e0 = fmaf(xr[0], w1, w0);
            float e1 = fmaf(xr[1], w1, w0);
            float e2 = fmaf(xr[2], w1, w0);
            #pragma unroll
            for (int tt = 0; tt < CHK; ++tt) {
                float e3 = fmaf(xr[tt+3], w1, w0);
                float acc = cb + e0*cw.x + e1*cw.y + e2*cw.z + e3*cw.w;
                xw[tt*XCP + ch] = silu_f(acc);
                e0 = e1; e1 = e2; e2 = e3;
            }
        }
    }
    __syncthreads();

    // ---- main loop: [A2(c) || conv(c+1)] | bar | scan(c) | bar ----
    v2f h01={0,0},h23={0,0},h45={0,0},h67={0,0},
        h89={0,0},hAB={0,0},hCD={0,0},hEF={0,0};
    float dacc = 0.f;

    for (int c = 0; c < NCH; ++c) {
        const int buf = c & 1;

        if (tid < 120) {
            // pair-A2: 1 xproj column pair (broadcast in 12-lane span),
            // 2 xrows (one per local group). Reads buf.
            const int j0 = a2jp*2;
            const float* p0  = &xprojT[j0*XCP];
            const float* p1  = &xprojT[(j0+1)*XCP];
            const float* xra = &xcbuf[buf][0][a2tt*XCP];
            const float* xrb = &xcbuf[buf][1][a2tt*XCP];
            v2f a0a={0,0}, a1a={0,0}, a0b={0,0}, a1b={0,0};
            #pragma unroll 4
            for (int d = 0; d < DINNER; d += 4) {
                float4 q0 = *(const float4*)(p0 + d);
                float4 q1 = *(const float4*)(p1 + d);
                float4 xa = *(const float4*)(xra + d);
                float4 xb = *(const float4*)(xrb + d);
                v2f q0l={q0.x,q0.y}, q0h={q0.z,q0.w};
                v2f q1l={q1.x,q1.y}, q1h={q1.z,q1.w};
                v2f xal={xa.x,xa.y}, xah={xa.z,xa.w};
                v2f xbl={xb.x,xb.y}, xbh={xb.z,xb.w};
                a0a = __builtin_elementwise_fma(xal, q0l, a0a);
                a0a = __builtin_elementwise_fma(xah, q0h, a0a);
                a1a = __builtin_elementwise_fma(xal, q1l, a1a);
                a1a = __builtin_elementwise_fma(xah, q1h, a1a);
                a0b = __builtin_elementwise_fma(xbl, q0l, a0b);
                a0b = __builtin_elementwise_fma(xbh, q0h, a0b);
                a1b = __builtin_elementwise_fma(xbl, q1l, a1b);
                a1b = __builtin_elementwise_fma(xbh, q1h, a1b);
            }
            float r0a=a0a.x+a0a.y, r1a=a1a.x+a1a.y;
            float r0b=a0b.x+a0b.y, r1b=a1b.x+a1b.y;
            if (j0 < 4) {
                *(float2*)&dtraw[0][a2tt][j0] = make_float2(r0a, r1a);
                *(float2*)&dtraw[1][a2tt][j0] = make_float2(r0b, r1b);
            } else {
                *(float2*)&Bsh[0][a2tt][j0-4] = make_float2(r0a, r1a);
                *(float2*)&Bsh[1][a2tt][j0-4] = make_float2(r0b, r1b);
            }
        } else if (tid >= 128 && c + 1 < NCH) {
            // dual-conv: chunk c+1 for both local groups into buf^1.
            #pragma unroll
            for (int q = 0; q < 2; ++q) {
                float* xw = &xcbuf[buf^1][q][0];
                const float* xr = &xrl[q*GSEG + (c+1)*CHK];
                float e0 = fmaf(xr[0], w1, w0);
                float e1 = fmaf(xr[1], w1, w0);
                float e2 = fmaf(xr[2], w1, w0);
                float v = 0.f;
                #pragma unroll
                for (int tt = 0; tt < CHK; ++tt) {
                    float e3 = fmaf(xr[tt+3], w1, w0);
                    float acc = cb + e0*cw.x + e1*cw.y + e2*cw.z + e3*cw.w;
                    v = silu_f(acc);
                    xw[tt*XCP + cch] = v;
                    e0 = e1; e1 = e2; e2 = e3;
                }
                if (half == 1 && q == 1 && c + 1 == NCH-1)
                    ws[(size_t)batch*WSB + 4352 + cch] = v;       // xc at t=335
            }
        }
        __syncthreads();   // dtraw/Bsh(c) + conv(c+1) ready

        // ---- phase 2: pure scan chunk c (reads buf) ----
        const float* xs = &xcbuf[buf][gl][0];
        if (__builtin_expect(sfast, 1)) {
            #pragma unroll
            for (int tt = 0; tt < CHK; ++tt) {
                float4 dr = *(const float4*)&dtraw[gl][tt][0];   // broadcast
                float dv = fmaf(dr.x, dtw0, fmaf(dr.y, dtw1,
                           fmaf(dr.z, dtw2, fmaf(dr.w, dtw3, dtb_r))));
                float e  = __expf(dv);
                float p  = 1.f + e;
                float r  = fast_rcp(p);                  // exp(-delta)
                float dl = (dv > 80.f) ? dv : __logf(p); // delta
                dacc += dl;
                float ux = dl * xs[tt*XCP + ch];
                float4 B0 = *(const float4*)&Bsh[gl][tt][0];
                float4 B1 = *(const float4*)&Bsh[gl][tt][4];
                float4 B2 = *(const float4*)&Bsh[gl][tt][8];
                float4 B3 = *(const float4*)&Bsh[gl][tt][12];
                float r2 = r*r, r4 = r2*r2, r8 = r4*r4;
                v2f r2v = {r2, r2}, r4v = {r4, r4}, r8v = {r8, r8};
                v2f p01 = {r, r2};
                v2f p23 = p01*r2v;
                v2f p45 = p01*r4v, p67 = p23*r4v;
                v2f p89 = p01*r8v, pAB = p23*r8v, pCD = p45*r8v, pEF = p67*r8v;
                v2f uxv = {ux, ux};
                h01 = __builtin_elementwise_fma(p01, h01, uxv*(v2f){B0.x,B0.y});
                h23 = __builtin_elementwise_fma(p23, h23, uxv*(v2f){B0.z,B0.w});
                h45 = __builtin_elementwise_fma(p45, h45, uxv*(v2f){B1.x,B1.y});
                h67 = __builtin_elementwise_fma(p67, h67, uxv*(v2f){B1.z,B1.w});
                h89 = __builtin_elementwise_fma(p89, h89, uxv*(v2f){B2.x,B2.y});
                hAB = __builtin_elementwise_fma(pAB, hAB, uxv*(v2f){B2.z,B2.w});
                hCD = __builtin_elementwise_fma(pCD, hCD, uxv*(v2f){B3.x,B3.y});
                hEF = __builtin_elementwise_fma(pEF, hEF, uxv*(v2f){B3.z,B3.w});
            }
        } else {
            const float* Arow = A_log + ch*DSTATE;
            for (int tt = 0; tt < CHK; ++tt) {
                float4 dr = *(const float4*)&dtraw[gl][tt][0];
                float dv = fmaf(dr.x, dtw0, fmaf(dr.y, dtw1,
                           fmaf(dr.z, dtw2, fmaf(dr.w, dtw3, dtb_r))));
                float e  = __expf(dv);
                float dl = (dv > 15.f) ? dv : __logf(1.f + e);
                dacc += dl;
                float ux = dl * xs[tt*XCP + ch];
                const float* Brow = &Bsh[gl][tt][0];
                float hv[16] = {h01.x,h01.y,h23.x,h23.y,h45.x,h45.y,h67.x,h67.y,
                                h89.x,h89.y,hAB.x,hAB.y,hCD.x,hCD.y,hEF.x,hEF.y};
                for (int i = 0; i < 16; ++i)
                    hv[i] = fmaf(__expf(-__expf(Arow[i])*dl), hv[i], ux*Brow[i]);
                h01=(v2f){hv[0],hv[1]};   h23=(v2f){hv[2],hv[3]};
                h45=(v2f){hv[4],hv[5]};   h67=(v2f){hv[6],hv[7]};
                h89=(v2f){hv[8],hv[9]};   hAB=(v2f){hv[10],hv[11]};
                hCD=(v2f){hv[12],hv[13]}; hEF=(v2f){hv[14],hv[15]};
            }
        }
        __syncthreads();   // scan reads done before next A2/conv overwrite
    }

    // ---- in-block 2-segment merge (gl=1 absorbs gl=0), export partial ----
    float* hpart = &xcbuf[0][0][0];      // 128 recs x HSTR = 2560 <= 6336
    float* dsum  = &Bsh[0][0][0];        // 128 <= 384
    if (gl == 0) {
        float4* hp = (float4*)&hpart[ch*HSTR];
        hp[0] = make_float4(h01.x,h01.y,h23.x,h23.y);
        hp[1] = make_float4(h45.x,h45.y,h67.x,h67.y);
        hp[2] = make_float4(h89.x,h89.y,hAB.x,hAB.y);
        hp[3] = make_float4(hCD.x,hCD.y,hEF.x,hEF.y);
        dsum[ch] = dacc;
    }
    __syncthreads();
    if (gl == 1) {
        const float4* hp = (const float4*)&hpart[ch*HSTR];
        float4 a = hp[0], bq = hp[1], cq = hp[2], dq = hp[3];
        float h0[16] = {a.x,a.y,a.z,a.w,bq.x,bq.y,bq.z,bq.w,
                        cq.x,cq.y,cq.z,cq.w,dq.x,dq.y,dq.z,dq.w};
        float h1[16] = {h01.x,h01.y,h23.x,h23.y,h45.x,h45.y,h67.x,h67.y,
                        h89.x,h89.y,hAB.x,hAB.y,hCD.x,hCD.y,hEF.x,hEF.y};
        float P[16];
        if (structured) {
            float r = __expf(-dacc);
            float pw = 1.f;
            #pragma unroll
            for (int i = 0; i < 16; ++i) { pw *= r; P[i] = fmaf(pw, h0[i], h1[i]); }
        } else {
            #pragma unroll
            for (int i = 0; i < 16; ++i)
                P[i] = fmaf(__expf(-__expf(A_log[ch*DSTATE+i])*dacc), h0[i], h1[i]);
        }
        float* wsb = ws + (size_t)batch*WSB + half*2176;
        float4* pw4 = (float4*)(wsb + ch*16);
        pw4[0] = make_float4(P[0],P[1],P[2],P[3]);
        pw4[1] = make_float4(P[4],P[5],P[6],P[7]);
        pw4[2] = make_float4(P[8],P[9],P[10],P[11]);
        pw4[3] = make_float4(P[12],P[13],P[14],P[15]);
        wsb[2048 + ch] = dsum[ch] + dacc;    // D(seg a) + D(seg b)
    }
}

// R12 kernel 2: per-batch combine of the two half-partials + full epilogue.
// Kernel boundary provides the cross-block fence (one amortized L2 writeback).
__global__ __launch_bounds__(128, 2) void mamba_epi(
    const float* __restrict__ x_raw,   const float* __restrict__ x_features,
    const float* __restrict__ embed_W, const float* __restrict__ embed_b,
    const float* __restrict__ in_W,    const float* __restrict__ xproj_W,
    const float* __restrict__ A_log,   const float* __restrict__ Dvec,
    const float* __restrict__ out_W,
    const float* __restrict__ mlp_W1,  const float* __restrict__ mlp_b1,
    const float* __restrict__ mlp_W2,  const float* __restrict__ mlp_b2,
    const float* __restrict__ head_W,  const float* __restrict__ head_b,
    const float* __restrict__ ws,      float* __restrict__ out)
{
    __shared__ float xcl[DINNER], Cpart[8][16], Cl[DSTATE], yv[DINNER];
    __shared__ float hfin[96], mlph[MLPH];

    const int ch = threadIdx.x;
    const int b  = blockIdx.x;
    const float* wsb = ws + (size_t)b*WSB;

    // stage xcl; combine H = r(D23)^k * P01 + P23; z-gate (all independent)
    xcl[ch] = wsb[4352 + ch];

    bool structured = true;
    #pragma unroll
    for (int i = 0; i < 16; ++i) {
        float a = __expf(A_log[ch*DSTATE + i]);
        float ex = (float)(i + 1);
        structured = structured && (fabsf(a - ex) < 1e-3f * ex);
    }

    float H[16];
    {
        const float4* p01 = (const float4*)(wsb + ch*16);
        const float4* p23 = (const float4*)(wsb + 2176 + ch*16);
        float D23 = wsb[2176 + 2048 + ch];
        float4 a0 = p01[0], a1 = p01[1], a2 = p01[2], a3 = p01[3];
        float4 b0 = p23[0], b1 = p23[1], b2 = p23[2], b3 = p23[3];
        float P0[16] = {a0.x,a0.y,a0.z,a0.w,a1.x,a1.y,a1.z,a1.w,
                        a2.x,a2.y,a2.z,a2.w,a3.x,a3.y,a3.z,a3.w};
        float P1[16] = {b0.x,b0.y,b0.z,b0.w,b1.x,b1.y,b1.z,b1.w,
                        b2.x,b2.y,b2.z,b2.w,b3.x,b3.y,b3.z,b3.w};
        if (structured) {
            float r = __expf(-D23);
            float pw = 1.f;
            #pragma unroll
            for (int i = 0; i < 16; ++i) { pw *= r; H[i] = fmaf(pw, P0[i], P1[i]); }
        } else {
            #pragma unroll
            for (int i = 0; i < 16; ++i)
                H[i] = fmaf(__expf(-__expf(A_log[ch*DSTATE+i])*D23), P0[i], P1[i]);
        }
    }

    float zs;
    {
        float a1 = 0.f, a0 = 0.f;
        for (int dm = 0; dm < DMODEL; ++dm) {
            float w = in_W[dm*(2*DINNER) + DINNER + ch];
            a1 = fmaf(embed_W[dm], w, a1);
            a0 = fmaf(embed_b[dm], w, a0);
        }
        zs = silu_f(fmaf(x_raw[b*LOOKBACK + 335], a1, a0));
    }
    __syncthreads();   // xcl ready

    // C partials: 8 d-slices x 16 n
    {
        const int q = ch >> 4, n = ch & 15;
        float acc = 0.f;
        for (int d = q*16; d < q*16 + 16; ++d)
            acc = fmaf(xcl[d], xproj_W[d*36 + 20 + n], acc);
        Cpart[q][n] = acc;
    }
    __syncthreads();

    // Cl-sum (16 lanes) | mlp1 (64 lanes, full 164-dot)
    if (ch < 16) {
        float s = 0.f;
        #pragma unroll
        for (int q = 0; q < 8; ++q) s += Cpart[q][ch];
        Cl[ch] = s;
    } else if (ch >= 64) {
        const int j = ch - 64;
        const float* xf = x_features + b*NFEAT;
        float acc = 0.f;
        for (int f = 0; f < NFEAT; ++f)
            acc = fmaf(xf[f], mlp_W1[f*MLPH + j], acc);
        mlph[j] = fmaxf(acc + mlp_b1[j], 0.f);
    }
    __syncthreads();

    // y
    {
        float acc = 0.f;
        #pragma unroll
        for (int i = 0; i < 16; ++i) acc = fmaf(H[i], Cl[i], acc);
        float y = acc + xcl[ch]*Dvec[ch];
        yv[ch] = y * zs;
    }
    __syncthreads();

    // out projection: 64 outs x 2 k-lanes
    {
        const int o = ch >> 1, k = ch & 1;
        float acc = 0.f;
        for (int d = k*64; d < k*64 + 64; ++d)
            acc = fmaf(yv[d], out_W[d*DMODEL + o], acc);
        acc += __shfl_xor(acc, 1);
        if (k == 0) hfin[o] = acc;
    }
    __syncthreads();

    // mlp2
    if (ch < 64) {
        const int j = ch >> 1, k = ch & 1;
        float acc = 0.f;
        for (int kk = k*32; kk < k*32 + 32; ++kk)
            acc = fmaf(mlph[kk], mlp_W2[kk*32 + j], acc);
        acc += __shfl_xor(acc, 1);
        if (k == 0) hfin[64 + j] = acc + mlp_b2[j];
    }
    __syncthreads();

    // head
    if (ch < HORIZON) {
        float acc = 0.f;
        for (int i = 0; i < 96; ++i)
            acc = fmaf(hfin[i], head_W[i*HORIZON + ch], acc);
        out[b*HORIZON + ch] = acc + head_b[ch];
    }
}

extern "C" void kernel_launch(void* const* d_in, const int* in_sizes, int n_in,
                              void* d_out, int out_size, void* d_ws, size_t ws_size,
                              hipStream_t stream) {
    (void)in_sizes; (void)n_in; (void)out_size; (void)ws_size;
    float* ws = (float*)d_ws;
    mamba_scan2<<<BATCH*2, 256, 0, stream>>>(
        (const float*)d_in[0],
        (const float*)d_in[2],  (const float*)d_in[3],  (const float*)d_in[4],
        (const float*)d_in[5],  (const float*)d_in[6],  (const float*)d_in[7],
        (const float*)d_in[8],  (const float*)d_in[9],  (const float*)d_in[10],
        ws);
    mamba_epi<<<BATCH, 128, 0, stream>>>(
        (const float*)d_in[0],  (const float*)d_in[1],  (const float*)d_in[2],
        (const float*)d_in[3],  (const float*)d_in[4],  (const float*)d_in[7],
        (const float*)d_in[10], (const float*)d_in[11], (const float*)d_in[12],
        (const float*)d_in[13], (const float*)d_in[14], (const float*)d_in[15],
        (const float*)d_in[16], (const float*)d_in[17], (const float*)d_in[18],
        ws, (float*)d_out);
}

// Round 13
// 172.999 us; speedup vs baseline: 1.0193x; 1.0193x over previous
//
#include <hip/hip_runtime.h>
#include <math.h>

#define LOOKBACK 336
#define NFEAT    164
#define HORIZON  96
#define DMODEL   64
#define DSTATE   16
#define DINNER   128
#define MLPH     64
#define BATCH    512
#define XCP      132
#define NGL      2      // local groups (time segments) per block
#define GSEG     84     // timesteps per segment
#define CHK      12     // timesteps per chunk
#define NCH      7      // chunks per segment
#define HSTR     20     // hpart record stride
// ws floats per batch:
//   [half*2176 .. +2048) P_half[128][16]; [+2048..+2176) D_half[128]
//   [4352) xcl[128]; [4480) zsil[128]; [4608) mlph[64]; [4672) Cl[16]
#define WSB      4736

typedef float v2f __attribute__((ext_vector_type(2)));

__device__ __forceinline__ float fast_rcp(float x) { return __builtin_amdgcn_rcpf(x); }
__device__ __forceinline__ float silu_f(float x) {
    return x * fast_rcp(1.f + __expf(-x));
}

// R13 kernel 1 = R12 scan2 (verified 79us, VALU 62%) + post-loop task hoist:
// half-0 blocks compute z-gate + mlp1 after exporting their partial; half-1
// blocks compute the C-projection from xcl (stashed in LDS). Post-loop code
// cannot raise the main loop's register peak (R10's spill was in-loop under
// a forced cap). Main loop byte-identical to R12.
__global__ __launch_bounds__(256, 2) void mamba_scan2(
    const float* __restrict__ x_raw,   const float* __restrict__ x_features,
    const float* __restrict__ embed_W, const float* __restrict__ embed_b,
    const float* __restrict__ in_W,
    const float* __restrict__ conv_W,  const float* __restrict__ conv_b,
    const float* __restrict__ xproj_W, const float* __restrict__ dt_W,
    const float* __restrict__ dt_b,    const float* __restrict__ A_log,
    const float* __restrict__ mlp_W1,  const float* __restrict__ mlp_b1,
    float* __restrict__ ws)
{
    __shared__ __align__(16) float xrl[172];            // xrl[i]=x(half*168-3+i)
    __shared__ __align__(16) float xprojT[20*XCP];      // 10.56 KB
    __shared__ __align__(16) float xcbuf[2][NGL][CHK*XCP]; // 25.3 KB double-buffered
    __shared__ __align__(16) float Bsh[NGL][CHK][DSTATE];
    __shared__ __align__(16) float dtraw[NGL][CHK][4];
    __shared__ __align__(16) float xcl_lds[DINNER];

    const int tid   = threadIdx.x;
    const int batch = blockIdx.x >> 1;
    const int half  = blockIdx.x & 1;    // segments {0,1} or {2,3}
    const int gl    = tid >> 7;          // local group 0..1 (2 waves each)
    const int ch    = tid & 127;

    // ---- staging ----
    for (int i = tid; i < 171; i += 256) {
        int t = half*168 + i - 3;
        xrl[i] = (t >= 0) ? x_raw[batch*LOOKBACK + t] : 0.f;
    }
    for (int idx = tid; idx < 20*DINNER; idx += 256) {
        int jj = idx >> 7, d = idx & 127;
        xprojT[jj*XCP + d] = xproj_W[d*36 + jj];
    }

    // ---- per-thread channel params ----
    float w1 = 0.f, w0 = 0.f;
    for (int dm = 0; dm < DMODEL; ++dm) {
        float w = in_W[dm*(2*DINNER) + ch];
        w1 = fmaf(embed_W[dm], w, w1);
        w0 = fmaf(embed_b[dm], w, w0);
    }
    const float4 cw = *(const float4*)&conv_W[ch*4];
    const float  cb = conv_b[ch];
    const float dtw0 = dt_W[ch],       dtw1 = dt_W[128 + ch],
                dtw2 = dt_W[256 + ch], dtw3 = dt_W[384 + ch];
    const float dtb_r = dt_b[ch];
    bool structured = true;
    #pragma unroll
    for (int i = 0; i < 16; ++i) {
        float a = __expf(A_log[ch*DSTATE + i]);
        float ex = (float)(i + 1);
        structured = structured && (fabsf(a - ex) < 1e-3f * ex);
    }
    const bool sfast = __all(structured);

    // pair-A2 decode (tid<120): 1 column pair x 1 tt, covers BOTH local groups
    const int a2jp = tid / 12;               // 0..9
    const int a2tt = tid - a2jp*12;          // 0..11
    const int cch = tid & 127;
    __syncthreads();   // xrl/xprojT ready

    // ---- conv chunk 0 into buffer 0 (all threads, own (gl,ch)) ----
    {
        float* xw = &xcbuf[0][gl][0];
        const float* xr = &xrl[gl*GSEG];
        if (half == 0 && gl == 0) {      // zero-padded taps at sequence start
            for (int tt = 0; tt < CHK; ++tt) {
                float acc = cb;
                if (tt >= 3) acc = fmaf(fmaf(xr[tt],   w1, w0), cw.x, acc);
                if (tt >= 2) acc = fmaf(fmaf(xr[tt+1], w1, w0), cw.y, acc);
                if (tt >= 1) acc = fmaf(fmaf(xr[tt+2], w1, w0), cw.z, acc);
                acc = fmaf(fmaf(xr[tt+3], w1, w0), cw.w, acc);
                xw[tt*XCP + ch] = silu_f(acc);
            }
        } else {
            float e0 = fmaf(xr[0], w1, w0);
            float e1 = fmaf(xr[1], w1, w0);
            float e2 = fmaf(xr[2], w1, w0);
            #pragma unroll
            for (int tt = 0; tt < CHK; ++tt) {
                float e3 = fmaf(xr[tt+3], w1, w0);
                float acc = cb + e0*cw.x + e1*cw.y + e2*cw.z + e3*cw.w;
                xw[tt*XCP + ch] = silu_f(acc);
                e0 = e1; e1 = e2; e2 = e3;
            }
        }
    }
    __syncthreads();

    // ---- main loop: [A2(c) || conv(c+1)] | bar | scan(c) | bar ----
    v2f h01={0,0},h23={0,0},h45={0,0},h67={0,0},
        h89={0,0},hAB={0,0},hCD={0,0},hEF={0,0};
    float dacc = 0.f;

    for (int c = 0; c < NCH; ++c) {
        const int buf = c & 1;

        if (tid < 120) {
            // pair-A2: 1 xproj column pair (broadcast in 12-lane span),
            // 2 xrows (one per local group). Reads buf.
            const int j0 = a2jp*2;
            const float* p0  = &xprojT[j0*XCP];
            const float* p1  = &xprojT[(j0+1)*XCP];
            const float* xra = &xcbuf[buf][0][a2tt*XCP];
            const float* xrb = &xcbuf[buf][1][a2tt*XCP];
            v2f a0a={0,0}, a1a={0,0}, a0b={0,0}, a1b={0,0};
            #pragma unroll 4
            for (int d = 0; d < DINNER; d += 4) {
                float4 q0 = *(const float4*)(p0 + d);
                float4 q1 = *(const float4*)(p1 + d);
                float4 xa = *(const float4*)(xra + d);
                float4 xb = *(const float4*)(xrb + d);
                v2f q0l={q0.x,q0.y}, q0h={q0.z,q0.w};
                v2f q1l={q1.x,q1.y}, q1h={q1.z,q1.w};
                v2f xal={xa.x,xa.y}, xah={xa.z,xa.w};
                v2f xbl={xb.x,xb.y}, xbh={xb.z,xb.w};
                a0a = __builtin_elementwise_fma(xal, q0l, a0a);
                a0a = __builtin_elementwise_fma(xah, q0h, a0a);
                a1a = __builtin_elementwise_fma(xal, q1l, a1a);
                a1a = __builtin_elementwise_fma(xah, q1h, a1a);
                a0b = __builtin_elementwise_fma(xbl, q0l, a0b);
                a0b = __builtin_elementwise_fma(xbh, q0h, a0b);
                a1b = __builtin_elementwise_fma(xbl, q1l, a1b);
                a1b = __builtin_elementwise_fma(xbh, q1h, a1b);
            }
            float r0a=a0a.x+a0a.y, r1a=a1a.x+a1a.y;
            float r0b=a0b.x+a0b.y, r1b=a1b.x+a1b.y;
            if (j0 < 4) {
                *(float2*)&dtraw[0][a2tt][j0] = make_float2(r0a, r1a);
                *(float2*)&dtraw[1][a2tt][j0] = make_float2(r0b, r1b);
            } else {
                *(float2*)&Bsh[0][a2tt][j0-4] = make_float2(r0a, r1a);
                *(float2*)&Bsh[1][a2tt][j0-4] = make_float2(r0b, r1b);
            }
        } else if (tid >= 128 && c + 1 < NCH) {
            // dual-conv: chunk c+1 for both local groups into buf^1.
            #pragma unroll
            for (int q = 0; q < 2; ++q) {
                float* xw = &xcbuf[buf^1][q][0];
                const float* xr = &xrl[q*GSEG + (c+1)*CHK];
                float e0 = fmaf(xr[0], w1, w0);
                float e1 = fmaf(xr[1], w1, w0);
                float e2 = fmaf(xr[2], w1, w0);
                float v = 0.f;
                #pragma unroll
                for (int tt = 0; tt < CHK; ++tt) {
                    float e3 = fmaf(xr[tt+3], w1, w0);
                    float acc = cb + e0*cw.x + e1*cw.y + e2*cw.z + e3*cw.w;
                    v = silu_f(acc);
                    xw[tt*XCP + cch] = v;
                    e0 = e1; e1 = e2; e2 = e3;
                }
                if (half == 1 && q == 1 && c + 1 == NCH-1) {
                    ws[(size_t)batch*WSB + 4352 + cch] = v;       // xc at t=335
                    xcl_lds[cch] = v;
                }
            }
        }
        __syncthreads();   // dtraw/Bsh(c) + conv(c+1) ready

        // ---- phase 2: pure scan chunk c (reads buf) ----
        const float* xs = &xcbuf[buf][gl][0];
        if (__builtin_expect(sfast, 1)) {
            #pragma unroll
            for (int tt = 0; tt < CHK; ++tt) {
                float4 dr = *(const float4*)&dtraw[gl][tt][0];   // broadcast
                float dv = fmaf(dr.x, dtw0, fmaf(dr.y, dtw1,
                           fmaf(dr.z, dtw2, fmaf(dr.w, dtw3, dtb_r))));
                float e  = __expf(dv);
                float p  = 1.f + e;
                float r  = fast_rcp(p);                  // exp(-delta)
                float dl = (dv > 80.f) ? dv : __logf(p); // delta
                dacc += dl;
                float ux = dl * xs[tt*XCP + ch];
                float4 B0 = *(const float4*)&Bsh[gl][tt][0];
                float4 B1 = *(const float4*)&Bsh[gl][tt][4];
                float4 B2 = *(const float4*)&Bsh[gl][tt][8];
                float4 B3 = *(const float4*)&Bsh[gl][tt][12];
                float r2 = r*r, r4 = r2*r2, r8 = r4*r4;
                v2f r2v = {r2, r2}, r4v = {r4, r4}, r8v = {r8, r8};
                v2f p01 = {r, r2};
                v2f p23 = p01*r2v;
                v2f p45 = p01*r4v, p67 = p23*r4v;
                v2f p89 = p01*r8v, pAB = p23*r8v, pCD = p45*r8v, pEF = p67*r8v;
                v2f uxv = {ux, ux};
                h01 = __builtin_elementwise_fma(p01, h01, uxv*(v2f){B0.x,B0.y});
                h23 = __builtin_elementwise_fma(p23, h23, uxv*(v2f){B0.z,B0.w});
                h45 = __builtin_elementwise_fma(p45, h45, uxv*(v2f){B1.x,B1.y});
                h67 = __builtin_elementwise_fma(p67, h67, uxv*(v2f){B1.z,B1.w});
                h89 = __builtin_elementwise_fma(p89, h89, uxv*(v2f){B2.x,B2.y});
                hAB = __builtin_elementwise_fma(pAB, hAB, uxv*(v2f){B2.z,B2.w});
                hCD = __builtin_elementwise_fma(pCD, hCD, uxv*(v2f){B3.x,B3.y});
                hEF = __builtin_elementwise_fma(pEF, hEF, uxv*(v2f){B3.z,B3.w});
            }
        } else {
            const float* Arow = A_log + ch*DSTATE;
            for (int tt = 0; tt < CHK; ++tt) {
                float4 dr = *(const float4*)&dtraw[gl][tt][0];
                float dv = fmaf(dr.x, dtw0, fmaf(dr.y, dtw1,
                           fmaf(dr.z, dtw2, fmaf(dr.w, dtw3, dtb_r))));
                float e  = __expf(dv);
                float dl = (dv > 15.f) ? dv : __logf(1.f + e);
                dacc += dl;
                float ux = dl * xs[tt*XCP + ch];
                const float* Brow = &Bsh[gl][tt][0];
                float hv[16] = {h01.x,h01.y,h23.x,h23.y,h45.x,h45.y,h67.x,h67.y,
                                h89.x,h89.y,hAB.x,hAB.y,hCD.x,hCD.y,hEF.x,hEF.y};
                for (int i = 0; i < 16; ++i)
                    hv[i] = fmaf(__expf(-__expf(Arow[i])*dl), hv[i], ux*Brow[i]);
                h01=(v2f){hv[0],hv[1]};   h23=(v2f){hv[2],hv[3]};
                h45=(v2f){hv[4],hv[5]};   h67=(v2f){hv[6],hv[7]};
                h89=(v2f){hv[8],hv[9]};   hAB=(v2f){hv[10],hv[11]};
                hCD=(v2f){hv[12],hv[13]}; hEF=(v2f){hv[14],hv[15]};
            }
        }
        __syncthreads();   // scan reads done before next A2/conv overwrite
    }

    // ---- in-block 2-segment merge (gl=1 absorbs gl=0), export partial ----
    float* hpart = &xcbuf[0][0][0];      // 128 recs x HSTR = 2560 <= 6336
    float* dsum  = &Bsh[0][0][0];        // 128 floats
    float* Cpart = &Bsh[0][0][0] + 128;  // 128 floats (8 slices x 16 n)
    if (gl == 0) {
        float4* hp = (float4*)&hpart[ch*HSTR];
        hp[0] = make_float4(h01.x,h01.y,h23.x,h23.y);
        hp[1] = make_float4(h45.x,h45.y,h67.x,h67.y);
        hp[2] = make_float4(h89.x,h89.y,hAB.x,hAB.y);
        hp[3] = make_float4(hCD.x,hCD.y,hEF.x,hEF.y);
        dsum[ch] = dacc;
    }
    __syncthreads();
    if (gl == 1) {
        const float4* hp = (const float4*)&hpart[ch*HSTR];
        float4 a = hp[0], bq = hp[1], cq = hp[2], dq = hp[3];
        float h0[16] = {a.x,a.y,a.z,a.w,bq.x,bq.y,bq.z,bq.w,
                        cq.x,cq.y,cq.z,cq.w,dq.x,dq.y,dq.z,dq.w};
        float h1[16] = {h01.x,h01.y,h23.x,h23.y,h45.x,h45.y,h67.x,h67.y,
                        h89.x,h89.y,hAB.x,hAB.y,hCD.x,hCD.y,hEF.x,hEF.y};
        float P[16];
        if (structured) {
            float r = __expf(-dacc);
            float pw = 1.f;
            #pragma unroll
            for (int i = 0; i < 16; ++i) { pw *= r; P[i] = fmaf(pw, h0[i], h1[i]); }
        } else {
            #pragma unroll
            for (int i = 0; i < 16; ++i)
                P[i] = fmaf(__expf(-__expf(A_log[ch*DSTATE+i])*dacc), h0[i], h1[i]);
        }
        float* wsb = ws + (size_t)batch*WSB + half*2176;
        float4* pw4 = (float4*)(wsb + ch*16);
        pw4[0] = make_float4(P[0],P[1],P[2],P[3]);
        pw4[1] = make_float4(P[4],P[5],P[6],P[7]);
        pw4[2] = make_float4(P[8],P[9],P[10],P[11]);
        pw4[3] = make_float4(P[12],P[13],P[14],P[15]);
        wsb[2048 + ch] = dsum[ch] + dacc;    // D(seg a) + D(seg b)
    }

    // ---- post-loop task hoist (partial-independent epilogue pieces) ----
    if (half == 0) {
        if (tid < 128) {                     // z-gate, channel tid
            float a1 = 0.f, a0 = 0.f;
            for (int dm = 0; dm < DMODEL; ++dm) {
                float w = in_W[dm*(2*DINNER) + DINNER + tid];
                a1 = fmaf(embed_W[dm], w, a1);
                a0 = fmaf(embed_b[dm], w, a0);
            }
            float x335 = x_raw[batch*LOOKBACK + 335];
            ws[(size_t)batch*WSB + 4480 + tid] = silu_f(fmaf(x335, a1, a0));
        } else {                             // mlp1 (after export): 2 lanes/j
            const int lane = tid - 128;
            const int j = lane >> 1, k = lane & 1;
            const float* xf = x_features + batch*NFEAT;
            float acc = 0.f;
            const int f0 = k*82, f1 = (k ? NFEAT : 82);
            for (int f = f0; f < f1; ++f)
                acc = fmaf(xf[f], mlp_W1[f*MLPH + j], acc);
            acc += __shfl_xor(acc, 1);
            if (k == 0)
                ws[(size_t)batch*WSB + 4608 + j] = fmaxf(acc + mlp_b1[j], 0.f);
        }
    } else {
        // C-projection at t=335 from xcl_lds (written chunk NCH-2 phase 1)
        if (tid < 128) {
            const int q = tid >> 4, n = tid & 15;    // 8 d-slices x 16 n
            float acc = 0.f;
            for (int d = q*16; d < q*16 + 16; ++d)
                acc = fmaf(xcl_lds[d], xproj_W[d*36 + 20 + n], acc);
            Cpart[q*16 + n] = acc;
        }
        __syncthreads();
        if (tid < 16) {
            float s = 0.f;
            #pragma unroll
            for (int q = 0; q < 8; ++q) s += Cpart[q*16 + tid];
            ws[(size_t)batch*WSB + 4672 + tid] = s;
        }
    }
}

// R13 kernel 2: thin epilogue — combine + y + out + mlp2 + head.
// 256 threads, 2 barriers, ~110-FMA serial path (was ~400 at 128 threads).
__global__ __launch_bounds__(256, 2) void mamba_epi(
    const float* __restrict__ A_log,   const float* __restrict__ Dvec,
    const float* __restrict__ out_W,
    const float* __restrict__ mlp_W2,  const float* __restrict__ mlp_b2,
    const float* __restrict__ head_W,  const float* __restrict__ head_b,
    const float* __restrict__ ws,      float* __restrict__ out)
{
    __shared__ float yv[DINNER], hfin[96];

    const int tid = threadIdx.x;
    const int b   = blockIdx.x;
    const float* wsb = ws + (size_t)b*WSB;

    if (tid < 128) {
        const int ch = tid;
        bool structured = true;
        #pragma unroll
        for (int i = 0; i < 16; ++i) {
            float a = __expf(A_log[ch*DSTATE + i]);
            float ex = (float)(i + 1);
            structured = structured && (fabsf(a - ex) < 1e-3f * ex);
        }
        // H = P1 + r(D23)^k * P0
        const float4* p01 = (const float4*)(wsb + ch*16);
        const float4* p23 = (const float4*)(wsb + 2176 + ch*16);
        float D23 = wsb[2176 + 2048 + ch];
        float4 a0 = p01[0], a1 = p01[1], a2 = p01[2], a3 = p01[3];
        float4 b0 = p23[0], b1 = p23[1], b2 = p23[2], b3 = p23[3];
        float P0[16] = {a0.x,a0.y,a0.z,a0.w,a1.x,a1.y,a1.z,a1.w,
                        a2.x,a2.y,a2.z,a2.w,a3.x,a3.y,a3.z,a3.w};
        float P1[16] = {b0.x,b0.y,b0.z,b0.w,b1.x,b1.y,b1.z,b1.w,
                        b2.x,b2.y,b2.z,b2.w,b3.x,b3.y,b3.z,b3.w};
        float H[16];
        if (structured) {
            float r = __expf(-D23);
            float pw = 1.f;
            #pragma unroll
            for (int i = 0; i < 16; ++i) { pw *= r; H[i] = fmaf(pw, P0[i], P1[i]); }
        } else {
            #pragma unroll
            for (int i = 0; i < 16; ++i)
                H[i] = fmaf(__expf(-__expf(A_log[ch*DSTATE+i])*D23), P0[i], P1[i]);
        }
        // y = H·C + xc*D, gated
        const float* Cl = wsb + 4672;
        float acc = 0.f;
        #pragma unroll
        for (int i = 0; i < 16; ++i) acc = fmaf(H[i], Cl[i], acc);
        float y = acc + wsb[4352 + ch]*Dvec[ch];
        yv[ch] = y * wsb[4480 + ch];
    } else {
        // mlp2: 32 outs x 4 lanes (16 FMA + 2 shfl)
        const int lane = tid - 128;
        const int j = lane >> 2, k = lane & 3;
        const float* mlph = wsb + 4608;
        float acc = 0.f;
        for (int kk = k*16; kk < k*16 + 16; ++kk)
            acc = fmaf(mlph[kk], mlp_W2[kk*32 + j], acc);
        acc += __shfl_xor(acc, 1);
        acc += __shfl_xor(acc, 2);
        if (k == 0) hfin[64 + j] = acc + mlp_b2[j];
    }
    __syncthreads();

    // out projection: 64 outs x 4 lanes (32 FMA + 2 shfl)
    {
        const int o = tid >> 2, k = tid & 3;
        float acc = 0.f;
        for (int d = k*32; d < k*32 + 32; ++d)
            acc = fmaf(yv[d], out_W[d*DMODEL + o], acc);
        acc += __shfl_xor(acc, 1);
        acc += __shfl_xor(acc, 2);
        if (k == 0) hfin[o] = acc;
    }
    __syncthreads();

    // head: 96 outs x 2 lanes (48 FMA + 1 shfl)
    if (tid < 192) {
        const int o = tid >> 1, k = tid & 1;
        float acc = 0.f;
        for (int i = k*48; i < k*48 + 48; ++i)
            acc = fmaf(hfin[i], head_W[i*HORIZON + o], acc);
        acc += __shfl_xor(acc, 1);
        if (k == 0) out[b*HORIZON + o] = acc + head_b[o];
    }
}

extern "C" void kernel_launch(void* const* d_in, const int* in_sizes, int n_in,
                              void* d_out, int out_size, void* d_ws, size_t ws_size,
                              hipStream_t stream) {
    (void)in_sizes; (void)n_in; (void)out_size; (void)ws_size;
    float* ws = (float*)d_ws;
    mamba_scan2<<<BATCH*2, 256, 0, stream>>>(
        (const float*)d_in[0],  (const float*)d_in[1],
        (const float*)d_in[2],  (const float*)d_in[3],  (const float*)d_in[4],
        (const float*)d_in[5],  (const float*)d_in[6],  (const float*)d_in[7],
        (const float*)d_in[8],  (const float*)d_in[9],  (const float*)d_in[10],
        (const float*)d_in[13], (const float*)d_in[14],
        ws);
    mamba_epi<<<BATCH, 256, 0, stream>>>(
        (const float*)d_in[10], (const float*)d_in[11], (const float*)d_in[12],
        (const float*)d_in[15], (const float*)d_in[16], (const float*)d_in[17],
        (const float*)d_in[18], ws, (float*)d_out);
}